// Round 4
// baseline (1187.281 us; speedup 1.0000x reference)
//
#include <hip/hip_runtime.h>

#define NN 8192
#define FF 256
#define PST 136   // P LDS row stride in halves (128 + 8 pad, 16B-aligned)

typedef _Float16 h8 __attribute__((ext_vector_type(8)));
typedef _Float16 h4 __attribute__((ext_vector_type(4)));
typedef float    f4 __attribute__((ext_vector_type(4)));
typedef int      i4v __attribute__((ext_vector_type(4)));

// monotone float<->uint encoding for atomicMax on fp32
__device__ __forceinline__ unsigned fenc(float x) {
  unsigned u = __float_as_uint(x);
  return (u & 0x80000000u) ? ~u : (u | 0x80000000u);
}
__device__ __forceinline__ float fdec(unsigned e) {
  unsigned u = (e & 0x80000000u) ? (e ^ 0x80000000u) : ~e;
  return __uint_as_float(u);
}

// lgkm-only barrier (CK block_sync_lds pattern): publishes LDS writes without
// draining vmem (plain __syncthreads emits s_waitcnt vmcnt(0) -> kills the
// adj prefetch pipeline).
__device__ __forceinline__ void sync_lds() {
  __builtin_amdgcn_s_waitcnt(0xc07f);   // lgkmcnt(0), vmcnt/expcnt ignored
  __builtin_amdgcn_s_barrier();
}

// ---------------- Kernel 1: Wh = h@W (fp32 vector), s1, s2(f16), wfrag -------
// grid 512 x 256 thr. Block = 16 rows of h = half of k-tile (blockIdx>>1).
// wfrag[(kt*16+n)*512 + lane*8 + j] = Wh[kt*32 + (lane>>4)*8 + j][n*16 + (lane&15)]
__global__ __launch_bounds__(256) void k_wh(
    const float* __restrict__ h, const float* __restrict__ W,
    const float* __restrict__ a, _Float16* __restrict__ wfrag,
    float* __restrict__ s1, _Float16* __restrict__ s2h,
    unsigned* __restrict__ s2maxe) {
  __shared__ float hs[16 * 256];        // 16 KB
  __shared__ _Float16 whs[16 * 264];    // 8.25 KB
  const int t = threadIdx.x;
  const int r0 = blockIdx.x * 16;
#pragma unroll
  for (int i = 0; i < 4; ++i) {
    int idx = i * 1024 + t * 4;
    *(f4*)&hs[idx] = *(const f4*)&h[(size_t)r0 * 256 + idx];
  }
  __syncthreads();
  const int lane = t & 63;
  const int wv = t >> 6;        // 0..3
  const int rg = wv * 4;
  const int c4 = lane * 4;
  float acc[4][4];
#pragma unroll
  for (int i = 0; i < 4; ++i)
#pragma unroll
    for (int k = 0; k < 4; ++k) acc[i][k] = 0.f;
  f4 w[8];
#pragma unroll
  for (int i = 0; i < 8; ++i) w[i] = *(const f4*)&W[i * 256 + c4];
  for (int f = 0; f < 256; f += 8) {
    f4 nw[8];
    if (f < 248) {
#pragma unroll
      for (int i = 0; i < 8; ++i) nw[i] = *(const f4*)&W[(f + 8 + i) * 256 + c4];
    }
#pragma unroll
    for (int i = 0; i < 4; ++i) {
      f4 h0 = *(const f4*)&hs[(rg + i) * 256 + f];
      f4 h1 = *(const f4*)&hs[(rg + i) * 256 + f + 4];
#pragma unroll
      for (int k = 0; k < 4; ++k)
        acc[i][k] += h0[0]*w[0][k] + h0[1]*w[1][k] + h0[2]*w[2][k] + h0[3]*w[3][k]
                   + h1[0]*w[4][k] + h1[1]*w[5][k] + h1[2]*w[6][k] + h1[3]*w[7][k];
    }
    if (f < 248) {
#pragma unroll
      for (int i = 0; i < 8; ++i) w[i] = nw[i];
    }
  }
  float a1v[4], a2v[4];
#pragma unroll
  for (int k = 0; k < 4; ++k) { a1v[k] = a[c4 + k]; a2v[k] = a[256 + c4 + k]; }
#pragma unroll
  for (int i = 0; i < 4; ++i) {
    h4 hh;
    float p1 = 0.f, p2 = 0.f;
#pragma unroll
    for (int k = 0; k < 4; ++k) {
      hh[k] = (_Float16)acc[i][k];
      p1 += acc[i][k] * a1v[k];
      p2 += acc[i][k] * a2v[k];
    }
    *(h4*)&whs[(rg + i) * 264 + c4] = hh;
#pragma unroll
    for (int off = 32; off; off >>= 1) {
      p1 += __shfl_xor(p1, off);
      p2 += __shfl_xor(p2, off);
    }
    if (lane == 0) {
      const int r = r0 + rg + i;
      s1[r] = p1;
      s2h[r] = (_Float16)p2;
      atomicMax(s2maxe, fenc(p2));
    }
  }
  __syncthreads();
  {
    const int kt = blockIdx.x >> 1;
    const int hb = blockIdx.x & 1;
    const int lp = hb * 32 + (t & 31);
    const int kb = ((t & 31) >> 4) * 8;
    const int m16e = t & 15;
#pragma unroll
    for (int p = 0; p < 2; ++p) {
      const int n = (t >> 5) + p * 8;
      h8 v;
#pragma unroll
      for (int j = 0; j < 8; ++j) v[j] = whs[(kb + j) * 264 + n * 16 + m16e];
      *(h8*)&wfrag[(((size_t)kt * 16 + n) << 9) + lp * 8] = v;
    }
  }
}

// ---------------- Kernel 2: fused attention ----------------------------------
// grid 512 = (rt 0..127) x (kq 0..3); 512 thr; LB(512,4) -> 2 blocks/CU.
// Block: 64 rows x 256 cols x 2048 k. Period = 128 k (16 periods).
__global__ __launch_bounds__(512, 4) void k_gat(
    const int* __restrict__ adj, const _Float16* __restrict__ wfrag,
    const float* __restrict__ s1g, const _Float16* __restrict__ s2h,
    const unsigned* __restrict__ s2maxe,
    float* __restrict__ o0, float* __restrict__ o1,
    float* __restrict__ o2, float* __restrict__ o3,
    float* __restrict__ lbuf) {
  __shared__ _Float16 P[2][64 * PST];   // 34 KB
  __shared__ _Float16 s2l[2048];        // 4 KB
  const int t = threadIdx.x;
  const int lane = t & 63;
  const int w = t >> 6;          // 0..7: score rows {8w+q, 8w+q+4}; cols [32w,32w+32)
  const int q = lane >> 4;       // 0..3
  const int m16 = lane & 15;
  const int rt = (int)blockIdx.x >> 2;
  const int kq = (int)blockIdx.x & 3;
  const int r0 = rt * 64;

  if (t < 256) ((h8*)s2l)[t] = ((const h8*)(s2h + kq * 2048))[t];  // kq-quarter s2

  const int srA = 8 * w + q;                 // lane's two score rows (local)
  const int srB = srA + 4;
  const float s2m = fdec(*s2maxe);
  const float s1A = s1g[r0 + srA];
  const float s1B = s1g[r0 + srB];
  const float uA0 = s1A + s2m, uB0 = s1B + s2m;
  const float miA = fmaxf(uA0, 0.2f * uA0);  // >= leaky(s1+s2[j]) for all j
  const float miB = fmaxf(uB0, 0.2f * uB0);
  const float sAmi = s1A - miA, sBmi = s1B - miB;

  f4 acc[4][2];
#pragma unroll
  for (int m = 0; m < 4; ++m)
#pragma unroll
    for (int n = 0; n < 2; ++n)
#pragma unroll
      for (int e = 0; e < 4; ++e) acc[m][n][e] = 0.f;
  float lsA = 0.f, lsB = 0.f;

  const int* adjA = adj + (size_t)(r0 + srA) * NN + kq * 2048 + m16 * 8;
  const int* adjB = adj + (size_t)(r0 + srB) * NN + kq * 2048 + m16 * 8;
  __syncthreads();   // s2l ready (once; full drain harmless here)

  // preload adj for period 0
  i4v a0 = *(const i4v*)(adjA);
  i4v a1 = *(const i4v*)(adjA + 4);
  i4v b0 = *(const i4v*)(adjB);
  i4v b1 = *(const i4v*)(adjB + 4);

  for (int p = 0; p < 16; ++p) {
    // (1) B-frags for this period: 4 k-subtiles x 2 n-tiles, coalesced L2 loads
    const _Float16* wfb =
        wfrag + ((((size_t)(kq * 64 + p * 4)) * 16 + 2 * w) << 9) + lane * 8;
    h8 bb[8];
#pragma unroll
    for (int ks = 0; ks < 4; ++ks) {
      bb[2 * ks]     = *(const h8*)(wfb + ks * 8192);
      bb[2 * ks + 1] = *(const h8*)(wfb + ks * 8192 + 512);
    }
    // (2) adj prefetch for p+1 (HBM; consumed next period)
    i4v na0 = a0, na1 = a1, nb0 = b0, nb1 = b1;
    if (p < 15) {
      na0 = *(const i4v*)(adjA + (p + 1) * 128);
      na1 = *(const i4v*)(adjA + (p + 1) * 128 + 4);
      nb0 = *(const i4v*)(adjB + (p + 1) * 128);
      nb1 = *(const i4v*)(adjB + (p + 1) * 128 + 4);
    }
    // (3) scores for both rows: p = exp(leaky(s1+s2) - mi)
    const h8 s2c = *(const h8*)&s2l[p * 128 + m16 * 8];
    h8 pA, pB;
#pragma unroll
    for (int j = 0; j < 8; ++j) {
      const float s2v = (float)s2c[j];
      const int mA = (j < 4) ? a0[j] : a1[j - 4];
      const int mB = (j < 4) ? b0[j] : b1[j - 4];
      const float uA = s1A + s2v;
      const float uB = s1B + s2v;
      const float argA = sAmi + s2v - 0.8f * fminf(uA, 0.f);
      const float argB = sBmi + s2v - 0.8f * fminf(uB, 0.f);
      const float pvA = (mA > 0) ? __expf(argA) : 0.f;
      const float pvB = (mB > 0) ? __expf(argB) : 0.f;
      lsA += pvA; pA[j] = (_Float16)pvA;
      lsB += pvB; pB[j] = (_Float16)pvB;
    }
    _Float16* Pb = &P[p & 1][0];
    *(h8*)&Pb[srA * PST + m16 * 8] = pA;
    *(h8*)&Pb[srB * PST + m16 * 8] = pB;
    // (4) publish P without draining vmem
    sync_lds();
    // (5) MFMA: A from LDS (4 m-tiles), B from regs (issued at (1))
#pragma unroll
    for (int ks = 0; ks < 4; ++ks) {
      const h8 A0 = *(const h8*)&Pb[(     m16) * PST + ks * 32 + q * 8];
      const h8 A1 = *(const h8*)&Pb[(16 + m16) * PST + ks * 32 + q * 8];
      const h8 A2 = *(const h8*)&Pb[(32 + m16) * PST + ks * 32 + q * 8];
      const h8 A3 = *(const h8*)&Pb[(48 + m16) * PST + ks * 32 + q * 8];
      acc[0][0] = __builtin_amdgcn_mfma_f32_16x16x32_f16(A0, bb[2*ks],   acc[0][0], 0, 0, 0);
      acc[0][1] = __builtin_amdgcn_mfma_f32_16x16x32_f16(A0, bb[2*ks+1], acc[0][1], 0, 0, 0);
      acc[1][0] = __builtin_amdgcn_mfma_f32_16x16x32_f16(A1, bb[2*ks],   acc[1][0], 0, 0, 0);
      acc[1][1] = __builtin_amdgcn_mfma_f32_16x16x32_f16(A1, bb[2*ks+1], acc[1][1], 0, 0, 0);
      acc[2][0] = __builtin_amdgcn_mfma_f32_16x16x32_f16(A2, bb[2*ks],   acc[2][0], 0, 0, 0);
      acc[2][1] = __builtin_amdgcn_mfma_f32_16x16x32_f16(A2, bb[2*ks+1], acc[2][1], 0, 0, 0);
      acc[3][0] = __builtin_amdgcn_mfma_f32_16x16x32_f16(A3, bb[2*ks],   acc[3][0], 0, 0, 0);
      acc[3][1] = __builtin_amdgcn_mfma_f32_16x16x32_f16(A3, bb[2*ks+1], acc[3][1], 0, 0, 0);
    }
    a0 = na0; a1 = na1; b0 = nb0; b1 = nb1;
  }

  // partial softmax denominators: reduce over the 16 m16 lanes
  lsA += __shfl_xor(lsA, 1);
  lsA += __shfl_xor(lsA, 2);
  lsA += __shfl_xor(lsA, 4);
  lsA += __shfl_xor(lsA, 8);
  lsB += __shfl_xor(lsB, 1);
  lsB += __shfl_xor(lsB, 2);
  lsB += __shfl_xor(lsB, 4);
  lsB += __shfl_xor(lsB, 8);
  if (m16 == 0) {
    lbuf[kq * NN + r0 + srA] = lsA;
    lbuf[kq * NN + r0 + srB] = lsB;
  }

  // partial O: plain stores (each element written once per kq)
  float* ob = (kq == 0) ? o0 : (kq == 1) ? o1 : (kq == 2) ? o2 : o3;
#pragma unroll
  for (int m = 0; m < 4; ++m)
#pragma unroll
    for (int n = 0; n < 2; ++n)
#pragma unroll
      for (int v = 0; v < 4; ++v)
        ob[(size_t)(r0 + m * 16 + q * 4 + v) * FF + w * 32 + n * 16 + m16] =
            acc[m][n][v];
}

// ---------------- PROBE kernel: k_gat body repeated 3x (timing/counters only)
// Cracks the rocprof top-5 (~215 us) so k_gat's own hbm_gbps / VALUBusy /
// MfmaUtil / FETCH_SIZE become visible. adj re-read 3x (268 MB > L3 -> HBM).
__global__ __launch_bounds__(512, 4) void k_gat3(
    const int* __restrict__ adj, const _Float16* __restrict__ wfrag,
    const float* __restrict__ s1g, const _Float16* __restrict__ s2h,
    const unsigned* __restrict__ s2maxe,
    float* __restrict__ o0, float* __restrict__ lbuf) {
  __shared__ _Float16 P[2][64 * PST];
  __shared__ _Float16 s2l[2048];
  const int t = threadIdx.x;
  const int lane = t & 63;
  const int w = t >> 6;
  const int q = lane >> 4;
  const int m16 = lane & 15;
  const int rt = (int)blockIdx.x >> 2;
  const int kq = (int)blockIdx.x & 3;
  const int r0 = rt * 64;

  if (t < 256) ((h8*)s2l)[t] = ((const h8*)(s2h + kq * 2048))[t];

  const int srA = 8 * w + q;
  const int srB = srA + 4;
  const float s2m = fdec(*s2maxe);
  const float s1A = s1g[r0 + srA];
  const float s1B = s1g[r0 + srB];
  const float uA0 = s1A + s2m, uB0 = s1B + s2m;
  const float miA = fmaxf(uA0, 0.2f * uA0);
  const float miB = fmaxf(uB0, 0.2f * uB0);
  const float sAmi = s1A - miA, sBmi = s1B - miB;

  f4 acc[4][2];
#pragma unroll
  for (int m = 0; m < 4; ++m)
#pragma unroll
    for (int n = 0; n < 2; ++n)
#pragma unroll
      for (int e = 0; e < 4; ++e) acc[m][n][e] = 0.f;
  float lsA = 0.f, lsB = 0.f;

  const int* adjA = adj + (size_t)(r0 + srA) * NN + kq * 2048 + m16 * 8;
  const int* adjB = adj + (size_t)(r0 + srB) * NN + kq * 2048 + m16 * 8;
  __syncthreads();

  for (int rep = 0; rep < 3; ++rep) {
    i4v a0 = *(const i4v*)(adjA);
    i4v a1 = *(const i4v*)(adjA + 4);
    i4v b0 = *(const i4v*)(adjB);
    i4v b1 = *(const i4v*)(adjB + 4);

    for (int p = 0; p < 16; ++p) {
      const _Float16* wfb =
          wfrag + ((((size_t)(kq * 64 + p * 4)) * 16 + 2 * w) << 9) + lane * 8;
      h8 bb[8];
#pragma unroll
      for (int ks = 0; ks < 4; ++ks) {
        bb[2 * ks]     = *(const h8*)(wfb + ks * 8192);
        bb[2 * ks + 1] = *(const h8*)(wfb + ks * 8192 + 512);
      }
      i4v na0 = a0, na1 = a1, nb0 = b0, nb1 = b1;
      if (p < 15) {
        na0 = *(const i4v*)(adjA + (p + 1) * 128);
        na1 = *(const i4v*)(adjA + (p + 1) * 128 + 4);
        nb0 = *(const i4v*)(adjB + (p + 1) * 128);
        nb1 = *(const i4v*)(adjB + (p + 1) * 128 + 4);
      }
      const h8 s2c = *(const h8*)&s2l[p * 128 + m16 * 8];
      h8 pA, pB;
#pragma unroll
      for (int j = 0; j < 8; ++j) {
        const float s2v = (float)s2c[j];
        const int mA = (j < 4) ? a0[j] : a1[j - 4];
        const int mB = (j < 4) ? b0[j] : b1[j - 4];
        const float uA = s1A + s2v;
        const float uB = s1B + s2v;
        const float argA = sAmi + s2v - 0.8f * fminf(uA, 0.f);
        const float argB = sBmi + s2v - 0.8f * fminf(uB, 0.f);
        const float pvA = (mA > 0) ? __expf(argA) : 0.f;
        const float pvB = (mB > 0) ? __expf(argB) : 0.f;
        lsA += pvA; pA[j] = (_Float16)pvA;
        lsB += pvB; pB[j] = (_Float16)pvB;
      }
      _Float16* Pb = &P[p & 1][0];
      *(h8*)&Pb[srA * PST + m16 * 8] = pA;
      *(h8*)&Pb[srB * PST + m16 * 8] = pB;
      sync_lds();
#pragma unroll
      for (int ks = 0; ks < 4; ++ks) {
        const h8 A0 = *(const h8*)&Pb[(     m16) * PST + ks * 32 + q * 8];
        const h8 A1 = *(const h8*)&Pb[(16 + m16) * PST + ks * 32 + q * 8];
        const h8 A2 = *(const h8*)&Pb[(32 + m16) * PST + ks * 32 + q * 8];
        const h8 A3 = *(const h8*)&Pb[(48 + m16) * PST + ks * 32 + q * 8];
        acc[0][0] = __builtin_amdgcn_mfma_f32_16x16x32_f16(A0, bb[2*ks],   acc[0][0], 0, 0, 0);
        acc[0][1] = __builtin_amdgcn_mfma_f32_16x16x32_f16(A0, bb[2*ks+1], acc[0][1], 0, 0, 0);
        acc[1][0] = __builtin_amdgcn_mfma_f32_16x16x32_f16(A1, bb[2*ks],   acc[1][0], 0, 0, 0);
        acc[1][1] = __builtin_amdgcn_mfma_f32_16x16x32_f16(A1, bb[2*ks+1], acc[1][1], 0, 0, 0);
        acc[2][0] = __builtin_amdgcn_mfma_f32_16x16x32_f16(A2, bb[2*ks],   acc[2][0], 0, 0, 0);
        acc[2][1] = __builtin_amdgcn_mfma_f32_16x16x32_f16(A2, bb[2*ks+1], acc[2][1], 0, 0, 0);
        acc[3][0] = __builtin_amdgcn_mfma_f32_16x16x32_f16(A3, bb[2*ks],   acc[3][0], 0, 0, 0);
        acc[3][1] = __builtin_amdgcn_mfma_f32_16x16x32_f16(A3, bb[2*ks+1], acc[3][1], 0, 0, 0);
      }
      a0 = na0; a1 = na1; b0 = nb0; b1 = nb1;
    }
  }

  lsA += __shfl_xor(lsA, 1);
  lsA += __shfl_xor(lsA, 2);
  lsA += __shfl_xor(lsA, 4);
  lsA += __shfl_xor(lsA, 8);
  lsB += __shfl_xor(lsB, 1);
  lsB += __shfl_xor(lsB, 2);
  lsB += __shfl_xor(lsB, 4);
  lsB += __shfl_xor(lsB, 8);
  if (m16 == 0) {
    lbuf[kq * NN + r0 + srA] = lsA;
    lbuf[kq * NN + r0 + srB] = lsB;
  }
#pragma unroll
  for (int m = 0; m < 4; ++m)
#pragma unroll
    for (int n = 0; n < 2; ++n)
#pragma unroll
      for (int v = 0; v < 4; ++v)
        o0[(size_t)(r0 + m * 16 + q * 4 + v) * FF + w * 32 + n * 16 + m16] =
            acc[m][n][v];
}

// ---------------- Kernel 3: combine quarters, normalize, elu -----------------
__global__ __launch_bounds__(256) void k_fin(
    float* __restrict__ out, const float* __restrict__ o1,
    const float* __restrict__ o2, const float* __restrict__ o3,
    const float* __restrict__ lbuf) {
  const int t = threadIdx.x;
  const int row = blockIdx.x * 16 + (t >> 4);
  const int c0 = (t & 15) * 16;
  const float linv = 1.0f / (lbuf[row] + lbuf[NN + row] +
                             lbuf[2 * NN + row] + lbuf[3 * NN + row]);
#pragma unroll
  for (int i = 0; i < 4; ++i) {
    f4 v0 = *(const f4*)&out[(size_t)row * FF + c0 + i * 4];
    f4 v1 = *(const f4*)&o1[(size_t)row * FF + c0 + i * 4];
    f4 v2 = *(const f4*)&o2[(size_t)row * FF + c0 + i * 4];
    f4 v3 = *(const f4*)&o3[(size_t)row * FF + c0 + i * 4];
    f4 o;
#pragma unroll
    for (int e = 0; e < 4; ++e) {
      float x = (v0[e] + v1[e] + v2[e] + v3[e]) * linv;
      o[e] = (x > 0.f) ? x : (__expf(x) - 1.f);
    }
    *(f4*)&out[(size_t)row * FF + c0 + i * 4] = o;
  }
}

extern "C" void kernel_launch(void* const* d_in, const int* in_sizes, int n_in,
                              void* d_out, int out_size, void* d_ws, size_t ws_size,
                              hipStream_t stream) {
  const float* h   = (const float*)d_in[0];
  const int*   adj = (const int*)d_in[1];
  const float* W   = (const float*)d_in[2];
  const float* a   = (const float*)d_in[3];
  float* out = (float*)d_out;

  char* ws = (char*)d_ws;
  _Float16* wfrag = (_Float16*)ws;                                 // 4 MB
  float*    o1    = (float*)(ws + (4u << 20));                     // 8 MB (kq=1)
  float*    o2    = (float*)(ws + (12u << 20));                    // 8 MB (kq=2)
  float*    o3    = (float*)(ws + (20u << 20));                    // 8 MB (kq=3)
  float*    lbuf  = (float*)(ws + (28u << 20));                    // 128 KB (4 x 8192)
  unsigned* s2me  = (unsigned*)(ws + (28u << 20) + 131072);        // 4 B (+60 pad)
  float*    s1    = (float*)(ws + (28u << 20) + 131072 + 64);      // 32 KB
  _Float16* s2h   = (_Float16*)(ws + (28u << 20) + 131072 + 64 + 32768); // 16 KB

  // MEASUREMENT ROUND 2: real pipeline unchanged (504.6 us anchor), then
  // shadow probes into dummy buffers:
  //   1x k_gat3 (3x k-loop, ~218 us -> cracks rocprof top-5, exposes counters)
  //   4x k_wh   (idempotent rewrite of same values) -> t_wh
  //   2x k_fin  (dummy dst)                         -> t_fin
  float*    dumO  = (float*)(ws + (32u << 20));                    // 8 MB scratch
  float*    dumL  = (float*)(ws + (40u << 20));                    // 128 KB scratch

  hipMemsetAsync(s2me, 0, 4, stream);   // fenc-domain -inf
  k_wh<<<512, 256, 0, stream>>>(h, W, a, wfrag, s1, s2h, s2me);
  k_gat<<<512, 512, 0, stream>>>(adj, wfrag, s1, s2h, s2me, out, o1, o2, o3, lbuf);
  k_fin<<<512, 256, 0, stream>>>(out, o1, o2, o3, lbuf);

  // shadow probes (timing/counters only; outputs never read)
  k_gat3<<<512, 512, 0, stream>>>(adj, wfrag, s1, s2h, s2me, dumO, dumL);
  k_wh<<<512, 256, 0, stream>>>(h, W, a, wfrag, s1, s2h, s2me);
  k_wh<<<512, 256, 0, stream>>>(h, W, a, wfrag, s1, s2h, s2me);
  k_wh<<<512, 256, 0, stream>>>(h, W, a, wfrag, s1, s2h, s2me);
  k_wh<<<512, 256, 0, stream>>>(h, W, a, wfrag, s1, s2h, s2me);
  k_fin<<<512, 256, 0, stream>>>(dumO, o1, o2, o3, lbuf);
  k_fin<<<512, 256, 0, stream>>>(dumO, o1, o2, o3, lbuf);
}

// Round 5
// 418.715 us; speedup vs baseline: 2.8355x; 2.8355x over previous
//
#include <hip/hip_runtime.h>

#define NN 8192
#define FF 256
#define PST 136   // P LDS row stride in halves (128 + 8 pad, 16B-aligned)

typedef _Float16 h8 __attribute__((ext_vector_type(8)));
typedef _Float16 h4 __attribute__((ext_vector_type(4)));
typedef float    f4 __attribute__((ext_vector_type(4)));
typedef int      i4v __attribute__((ext_vector_type(4)));

// monotone float<->uint encoding for atomicMax on fp32
__device__ __forceinline__ unsigned fenc(float x) {
  unsigned u = __float_as_uint(x);
  return (u & 0x80000000u) ? ~u : (u | 0x80000000u);
}
__device__ __forceinline__ float fdec(unsigned e) {
  unsigned u = (e & 0x80000000u) ? (e ^ 0x80000000u) : ~e;
  return __uint_as_float(u);
}

// lgkm-only barrier (CK block_sync_lds pattern): publishes LDS writes without
// draining vmem (plain __syncthreads emits s_waitcnt vmcnt(0) -> kills the
// adj prefetch pipeline).
__device__ __forceinline__ void sync_lds() {
  __builtin_amdgcn_s_waitcnt(0xc07f);   // lgkmcnt(0), vmcnt/expcnt ignored
  __builtin_amdgcn_s_barrier();
}

// ---------------- Kernel 1: Wh = h@W (fp32 vector), s1, s2(f16), wfrag -------
// grid 512 x 256 thr. Block = 16 rows of h = half of k-tile (blockIdx>>1).
// wfrag[(kt*16+n)*512 + lane*8 + j] = Wh[kt*32 + (lane>>4)*8 + j][n*16 + (lane&15)]
// R4 fix: s2max via per-block LDS reduction + ONE atomicMax per block.
// Previous version did 8192 device-scope atomicMax to a single address
// (serialized across XCDs at the coherence point) -> ~90 us hidden tail.
__global__ __launch_bounds__(256) void k_wh(
    const float* __restrict__ h, const float* __restrict__ W,
    const float* __restrict__ a, _Float16* __restrict__ wfrag,
    float* __restrict__ s1, _Float16* __restrict__ s2h,
    unsigned* __restrict__ s2maxe) {
  __shared__ float hs[16 * 256];        // 16 KB
  __shared__ _Float16 whs[16 * 264];    // 8.25 KB
  __shared__ unsigned bm[4];            // per-wave p2-max (fenc domain)
  const int t = threadIdx.x;
  const int r0 = blockIdx.x * 16;
#pragma unroll
  for (int i = 0; i < 4; ++i) {
    int idx = i * 1024 + t * 4;
    *(f4*)&hs[idx] = *(const f4*)&h[(size_t)r0 * 256 + idx];
  }
  __syncthreads();
  const int lane = t & 63;
  const int wv = t >> 6;        // 0..3
  const int rg = wv * 4;
  const int c4 = lane * 4;
  float acc[4][4];
#pragma unroll
  for (int i = 0; i < 4; ++i)
#pragma unroll
    for (int k = 0; k < 4; ++k) acc[i][k] = 0.f;
  f4 w[8];
#pragma unroll
  for (int i = 0; i < 8; ++i) w[i] = *(const f4*)&W[i * 256 + c4];
  for (int f = 0; f < 256; f += 8) {
    f4 nw[8];
    if (f < 248) {
#pragma unroll
      for (int i = 0; i < 8; ++i) nw[i] = *(const f4*)&W[(f + 8 + i) * 256 + c4];
    }
#pragma unroll
    for (int i = 0; i < 4; ++i) {
      f4 h0 = *(const f4*)&hs[(rg + i) * 256 + f];
      f4 h1 = *(const f4*)&hs[(rg + i) * 256 + f + 4];
#pragma unroll
      for (int k = 0; k < 4; ++k)
        acc[i][k] += h0[0]*w[0][k] + h0[1]*w[1][k] + h0[2]*w[2][k] + h0[3]*w[3][k]
                   + h1[0]*w[4][k] + h1[1]*w[5][k] + h1[2]*w[6][k] + h1[3]*w[7][k];
    }
    if (f < 248) {
#pragma unroll
      for (int i = 0; i < 8; ++i) w[i] = nw[i];
    }
  }
  float a1v[4], a2v[4];
#pragma unroll
  for (int k = 0; k < 4; ++k) { a1v[k] = a[c4 + k]; a2v[k] = a[256 + c4 + k]; }
  unsigned wmax = 0u;   // fenc domain: 0 < fenc(x) for all finite x
#pragma unroll
  for (int i = 0; i < 4; ++i) {
    h4 hh;
    float p1 = 0.f, p2 = 0.f;
#pragma unroll
    for (int k = 0; k < 4; ++k) {
      hh[k] = (_Float16)acc[i][k];
      p1 += acc[i][k] * a1v[k];
      p2 += acc[i][k] * a2v[k];
    }
    *(h4*)&whs[(rg + i) * 264 + c4] = hh;
#pragma unroll
    for (int off = 32; off; off >>= 1) {
      p1 += __shfl_xor(p1, off);
      p2 += __shfl_xor(p2, off);
    }
    if (lane == 0) {
      const int r = r0 + rg + i;
      s1[r] = p1;
      s2h[r] = (_Float16)p2;
      const unsigned e = fenc(p2);
      wmax = (e > wmax) ? e : wmax;
    }
  }
  if (lane == 0) bm[wv] = wmax;
  __syncthreads();
  if (t == 0) {
    unsigned m01 = (bm[0] > bm[1]) ? bm[0] : bm[1];
    unsigned m23 = (bm[2] > bm[3]) ? bm[2] : bm[3];
    atomicMax(s2maxe, (m01 > m23) ? m01 : m23);   // 1 atomic per block (512 total)
  }
  {
    const int kt = blockIdx.x >> 1;
    const int hb = blockIdx.x & 1;
    const int lp = hb * 32 + (t & 31);
    const int kb = ((t & 31) >> 4) * 8;
    const int m16e = t & 15;
#pragma unroll
    for (int p = 0; p < 2; ++p) {
      const int n = (t >> 5) + p * 8;
      h8 v;
#pragma unroll
      for (int j = 0; j < 8; ++j) v[j] = whs[(kb + j) * 264 + n * 16 + m16e];
      *(h8*)&wfrag[(((size_t)kt * 16 + n) << 9) + lp * 8] = v;
    }
  }
}

// ---------------- Kernel 2: fused attention ----------------------------------
// grid 512 = (rt 0..127) x (kq 0..3); 512 thr; LB(512,4) -> 2 blocks/CU.
// Block: 64 rows x 256 cols x 2048 k. Period = 128 k (16 periods).
__global__ __launch_bounds__(512, 4) void k_gat(
    const int* __restrict__ adj, const _Float16* __restrict__ wfrag,
    const float* __restrict__ s1g, const _Float16* __restrict__ s2h,
    const unsigned* __restrict__ s2maxe,
    float* __restrict__ o0, float* __restrict__ o1,
    float* __restrict__ o2, float* __restrict__ o3,
    float* __restrict__ lbuf) {
  __shared__ _Float16 P[2][64 * PST];   // 34 KB
  __shared__ _Float16 s2l[2048];        // 4 KB
  const int t = threadIdx.x;
  const int lane = t & 63;
  const int w = t >> 6;          // 0..7: score rows {8w+q, 8w+q+4}; cols [32w,32w+32)
  const int q = lane >> 4;       // 0..3
  const int m16 = lane & 15;
  const int rt = (int)blockIdx.x >> 2;
  const int kq = (int)blockIdx.x & 3;
  const int r0 = rt * 64;

  if (t < 256) ((h8*)s2l)[t] = ((const h8*)(s2h + kq * 2048))[t];  // kq-quarter s2

  const int srA = 8 * w + q;                 // lane's two score rows (local)
  const int srB = srA + 4;
  const float s2m = fdec(*s2maxe);
  const float s1A = s1g[r0 + srA];
  const float s1B = s1g[r0 + srB];
  const float uA0 = s1A + s2m, uB0 = s1B + s2m;
  const float miA = fmaxf(uA0, 0.2f * uA0);  // >= leaky(s1+s2[j]) for all j
  const float miB = fmaxf(uB0, 0.2f * uB0);
  const float sAmi = s1A - miA, sBmi = s1B - miB;

  f4 acc[4][2];
#pragma unroll
  for (int m = 0; m < 4; ++m)
#pragma unroll
    for (int n = 0; n < 2; ++n)
#pragma unroll
      for (int e = 0; e < 4; ++e) acc[m][n][e] = 0.f;
  float lsA = 0.f, lsB = 0.f;

  const int* adjA = adj + (size_t)(r0 + srA) * NN + kq * 2048 + m16 * 8;
  const int* adjB = adj + (size_t)(r0 + srB) * NN + kq * 2048 + m16 * 8;
  __syncthreads();   // s2l ready (once; full drain harmless here)

  // preload adj for period 0
  i4v a0 = *(const i4v*)(adjA);
  i4v a1 = *(const i4v*)(adjA + 4);
  i4v b0 = *(const i4v*)(adjB);
  i4v b1 = *(const i4v*)(adjB + 4);

  for (int p = 0; p < 16; ++p) {
    // (1) B-frags for this period: 4 k-subtiles x 2 n-tiles, coalesced L2 loads
    const _Float16* wfb =
        wfrag + ((((size_t)(kq * 64 + p * 4)) * 16 + 2 * w) << 9) + lane * 8;
    h8 bb[8];
#pragma unroll
    for (int ks = 0; ks < 4; ++ks) {
      bb[2 * ks]     = *(const h8*)(wfb + ks * 8192);
      bb[2 * ks + 1] = *(const h8*)(wfb + ks * 8192 + 512);
    }
    // (2) adj prefetch for p+1 (HBM; consumed next period)
    i4v na0 = a0, na1 = a1, nb0 = b0, nb1 = b1;
    if (p < 15) {
      na0 = *(const i4v*)(adjA + (p + 1) * 128);
      na1 = *(const i4v*)(adjA + (p + 1) * 128 + 4);
      nb0 = *(const i4v*)(adjB + (p + 1) * 128);
      nb1 = *(const i4v*)(adjB + (p + 1) * 128 + 4);
    }
    // (3) scores for both rows: p = exp(leaky(s1+s2) - mi)
    const h8 s2c = *(const h8*)&s2l[p * 128 + m16 * 8];
    h8 pA, pB;
#pragma unroll
    for (int j = 0; j < 8; ++j) {
      const float s2v = (float)s2c[j];
      const int mA = (j < 4) ? a0[j] : a1[j - 4];
      const int mB = (j < 4) ? b0[j] : b1[j - 4];
      const float uA = s1A + s2v;
      const float uB = s1B + s2v;
      const float argA = sAmi + s2v - 0.8f * fminf(uA, 0.f);
      const float argB = sBmi + s2v - 0.8f * fminf(uB, 0.f);
      const float pvA = (mA > 0) ? __expf(argA) : 0.f;
      const float pvB = (mB > 0) ? __expf(argB) : 0.f;
      lsA += pvA; pA[j] = (_Float16)pvA;
      lsB += pvB; pB[j] = (_Float16)pvB;
    }
    _Float16* Pb = &P[p & 1][0];
    *(h8*)&Pb[srA * PST + m16 * 8] = pA;
    *(h8*)&Pb[srB * PST + m16 * 8] = pB;
    // (4) publish P without draining vmem
    sync_lds();
    // (5) MFMA: A from LDS (4 m-tiles), B from regs (issued at (1))
#pragma unroll
    for (int ks = 0; ks < 4; ++ks) {
      const h8 A0 = *(const h8*)&Pb[(     m16) * PST + ks * 32 + q * 8];
      const h8 A1 = *(const h8*)&Pb[(16 + m16) * PST + ks * 32 + q * 8];
      const h8 A2 = *(const h8*)&Pb[(32 + m16) * PST + ks * 32 + q * 8];
      const h8 A3 = *(const h8*)&Pb[(48 + m16) * PST + ks * 32 + q * 8];
      acc[0][0] = __builtin_amdgcn_mfma_f32_16x16x32_f16(A0, bb[2*ks],   acc[0][0], 0, 0, 0);
      acc[0][1] = __builtin_amdgcn_mfma_f32_16x16x32_f16(A0, bb[2*ks+1], acc[0][1], 0, 0, 0);
      acc[1][0] = __builtin_amdgcn_mfma_f32_16x16x32_f16(A1, bb[2*ks],   acc[1][0], 0, 0, 0);
      acc[1][1] = __builtin_amdgcn_mfma_f32_16x16x32_f16(A1, bb[2*ks+1], acc[1][1], 0, 0, 0);
      acc[2][0] = __builtin_amdgcn_mfma_f32_16x16x32_f16(A2, bb[2*ks],   acc[2][0], 0, 0, 0);
      acc[2][1] = __builtin_amdgcn_mfma_f32_16x16x32_f16(A2, bb[2*ks+1], acc[2][1], 0, 0, 0);
      acc[3][0] = __builtin_amdgcn_mfma_f32_16x16x32_f16(A3, bb[2*ks],   acc[3][0], 0, 0, 0);
      acc[3][1] = __builtin_amdgcn_mfma_f32_16x16x32_f16(A3, bb[2*ks+1], acc[3][1], 0, 0, 0);
    }
    a0 = na0; a1 = na1; b0 = nb0; b1 = nb1;
  }

  // partial softmax denominators: reduce over the 16 m16 lanes
  lsA += __shfl_xor(lsA, 1);
  lsA += __shfl_xor(lsA, 2);
  lsA += __shfl_xor(lsA, 4);
  lsA += __shfl_xor(lsA, 8);
  lsB += __shfl_xor(lsB, 1);
  lsB += __shfl_xor(lsB, 2);
  lsB += __shfl_xor(lsB, 4);
  lsB += __shfl_xor(lsB, 8);
  if (m16 == 0) {
    lbuf[kq * NN + r0 + srA] = lsA;
    lbuf[kq * NN + r0 + srB] = lsB;
  }

  // partial O: plain stores (each element written once per kq)
  float* ob = (kq == 0) ? o0 : (kq == 1) ? o1 : (kq == 2) ? o2 : o3;
#pragma unroll
  for (int m = 0; m < 4; ++m)
#pragma unroll
    for (int n = 0; n < 2; ++n)
#pragma unroll
      for (int v = 0; v < 4; ++v)
        ob[(size_t)(r0 + m * 16 + q * 4 + v) * FF + w * 32 + n * 16 + m16] =
            acc[m][n][v];
}

// ---------------- Kernel 3: combine quarters, normalize, elu -----------------
__global__ __launch_bounds__(256) void k_fin(
    float* __restrict__ out, const float* __restrict__ o1,
    const float* __restrict__ o2, const float* __restrict__ o3,
    const float* __restrict__ lbuf) {
  const int t = threadIdx.x;
  const int row = blockIdx.x * 16 + (t >> 4);
  const int c0 = (t & 15) * 16;
  const float linv = 1.0f / (lbuf[row] + lbuf[NN + row] +
                             lbuf[2 * NN + row] + lbuf[3 * NN + row]);
#pragma unroll
  for (int i = 0; i < 4; ++i) {
    f4 v0 = *(const f4*)&out[(size_t)row * FF + c0 + i * 4];
    f4 v1 = *(const f4*)&o1[(size_t)row * FF + c0 + i * 4];
    f4 v2 = *(const f4*)&o2[(size_t)row * FF + c0 + i * 4];
    f4 v3 = *(const f4*)&o3[(size_t)row * FF + c0 + i * 4];
    f4 o;
#pragma unroll
    for (int e = 0; e < 4; ++e) {
      float x = (v0[e] + v1[e] + v2[e] + v3[e]) * linv;
      o[e] = (x > 0.f) ? x : (__expf(x) - 1.f);
    }
    *(f4*)&out[(size_t)row * FF + c0 + i * 4] = o;
  }
}

extern "C" void kernel_launch(void* const* d_in, const int* in_sizes, int n_in,
                              void* d_out, int out_size, void* d_ws, size_t ws_size,
                              hipStream_t stream) {
  const float* h   = (const float*)d_in[0];
  const int*   adj = (const int*)d_in[1];
  const float* W   = (const float*)d_in[2];
  const float* a   = (const float*)d_in[3];
  float* out = (float*)d_out;

  char* ws = (char*)d_ws;
  _Float16* wfrag = (_Float16*)ws;                                 // 4 MB
  float*    o1    = (float*)(ws + (4u << 20));                     // 8 MB (kq=1)
  float*    o2    = (float*)(ws + (12u << 20));                    // 8 MB (kq=2)
  float*    o3    = (float*)(ws + (20u << 20));                    // 8 MB (kq=3)
  float*    lbuf  = (float*)(ws + (28u << 20));                    // 128 KB (4 x 8192)
  unsigned* s2me  = (unsigned*)(ws + (28u << 20) + 131072);        // 4 B (+60 pad)
  float*    s1    = (float*)(ws + (28u << 20) + 131072 + 64);      // 32 KB
  _Float16* s2h   = (_Float16*)(ws + (28u << 20) + 131072 + 64 + 32768); // 16 KB

  hipMemsetAsync(s2me, 0, 4, stream);   // fenc-domain -inf
  k_wh<<<512, 256, 0, stream>>>(h, W, a, wfrag, s1, s2h, s2me);
  k_gat<<<512, 512, 0, stream>>>(adj, wfrag, s1, s2h, s2me, out, o1, o2, o3, lbuf);
  k_fin<<<512, 256, 0, stream>>>(out, o1, o2, o3, lbuf);
}